// Round 1
// baseline (1318.943 us; speedup 1.0000x reference)
//
#include <hip/hip_runtime.h>

#define N_NODES 100000
#define N_EDGES 1600000
#define IN_CH   128
#define HID     64
#define NG      256

// ---- degree count: deg[dst] += 1 per edge (deg buffer pre-zeroed) ----
__global__ void k_deg(const int* __restrict__ dst, float* __restrict__ deg) {
    int e = blockIdx.x * blockDim.x + threadIdx.x;
    if (e < N_EDGES) atomicAdd(&deg[dst[e]], 1.0f);
}

// ---- dinv[i] = rsqrt(deg[i] + 1)  (in place) ----
__global__ void k_dinv(float* __restrict__ val) {
    int i = blockIdx.x * blockDim.x + threadIdx.x;
    if (i < N_NODES) val[i] = rsqrtf(val[i] + 1.0f);
}

// ---- out[i][j] = sum_k x[i*K+k] * W[k*64+j] ; one wave per node (64 j's) ----
template <int K>
__global__ void k_linear(const float* __restrict__ x, const float* __restrict__ W,
                         float* __restrict__ out) {
    int t = blockIdx.x * blockDim.x + threadIdx.x;
    int i = t >> 6;
    int j = t & 63;
    if (i >= N_NODES) return;
    const float* xr = x + (long)i * K;
    float acc = 0.f;
#pragma unroll 8
    for (int k = 0; k < K; ++k) acc = fmaf(xr[k], W[k * 64 + j], acc);
    out[(long)i * 64 + j] = acc;
}

// ---- scatter: agg[dst][j] += dinv[src]*dinv[dst] * h[src][j] ----
__global__ void k_agg(const int* __restrict__ src, const int* __restrict__ dst,
                      const float* __restrict__ dinv, const float* __restrict__ h,
                      float* __restrict__ agg) {
    int t = blockIdx.x * blockDim.x + threadIdx.x;
    int e = t >> 6;
    int j = t & 63;
    if (e >= N_EDGES) return;
    int s = src[e], d = dst[e];
    float norm = dinv[s] * dinv[d];
    atomicAdd(&agg[d * 64 + j], norm * h[s * 64 + j]);
}

// ---- agg = relu(agg + dinv^2 * h + b) in place ----
__global__ void k_finish(const float* __restrict__ h, const float* __restrict__ dinv,
                         const float* __restrict__ b, float* __restrict__ agg) {
    int t = blockIdx.x * blockDim.x + threadIdx.x;
    if (t >= N_NODES * HID) return;
    int i = t >> 6;
    int j = t & 63;
    float di = dinv[i];
    float v = agg[t] + di * di * h[t] + b[j];
    agg[t] = v > 0.f ? v : 0.f;
}

// ---- per-graph node count ----
__global__ void k_cnt(const int* __restrict__ batch, float* __restrict__ cnt) {
    int i = blockIdx.x * blockDim.x + threadIdx.x;
    if (i < N_NODES) atomicAdd(&cnt[batch[i]], 1.0f);
}

// ---- pooled[g][j] += a[i][j] ----
__global__ void k_pool(const int* __restrict__ batch, const float* __restrict__ a,
                       float* __restrict__ pooled) {
    int t = blockIdx.x * blockDim.x + threadIdx.x;
    if (t >= N_NODES * HID) return;
    int i = t >> 6;
    int j = t & 63;
    atomicAdd(&pooled[batch[i] * HID + j], a[t]);
}

// ---- head MLP: one 64-thread block per graph ----
__global__ void k_head(const float* __restrict__ pooled, const float* __restrict__ cnt,
                       const float* __restrict__ Wc1, const float* __restrict__ bc1,
                       const float* __restrict__ Wc2, const float* __restrict__ bc2,
                       float* __restrict__ out) {
    __shared__ float gvec[64];
    __shared__ float tvec[32];
    int g = blockIdx.x;
    int j = threadIdx.x;
    float c = cnt[g];
    c = c > 1.f ? c : 1.f;
    gvec[j] = pooled[g * 64 + j] / c;
    __syncthreads();
    if (j < 32) {
        float acc = bc1[j];
#pragma unroll 8
        for (int k = 0; k < 64; ++k) acc = fmaf(gvec[k], Wc1[k * 32 + j], acc);
        tvec[j] = acc > 0.f ? acc : 0.f;
    }
    __syncthreads();
    if (j < 2) {
        float acc = bc2[j];
#pragma unroll
        for (int k = 0; k < 32; ++k) acc = fmaf(tvec[k], Wc2[k * 2 + j], acc);
        out[g * 2 + j] = acc;
    }
}

extern "C" void kernel_launch(void* const* d_in, const int* in_sizes, int n_in,
                              void* d_out, int out_size, void* d_ws, size_t ws_size,
                              hipStream_t stream) {
    const float* x    = (const float*)d_in[0];
    const int*   ei   = (const int*)d_in[1];
    const int*   batch= (const int*)d_in[2];
    const float* W1   = (const float*)d_in[3];
    const float* b1   = (const float*)d_in[4];
    const float* W2   = (const float*)d_in[5];
    const float* b2   = (const float*)d_in[6];
    const float* Wc1  = (const float*)d_in[7];
    const float* bc1  = (const float*)d_in[8];
    const float* Wc2  = (const float*)d_in[9];
    const float* bc2  = (const float*)d_in[10];
    float* out = (float*)d_out;

    const int* src = ei;            // edge_index[0]
    const int* dst = ei + N_EDGES;  // edge_index[1]

    // workspace layout (all f32)
    char* ws = (char*)d_ws;
    const size_t HBYTES = (size_t)N_NODES * HID * sizeof(float);  // 25,600,000
    float* h      = (float*)(ws);
    float* agg    = (float*)(ws + HBYTES);
    float* dinv   = (float*)(ws + 2 * HBYTES);                 // N floats
    float* pooled = (float*)(ws + 2 * HBYTES + 400000);        // G*64
    float* cnt    = pooled + NG * HID;                         // G

    const int TB = 256;
    const int nNH   = N_NODES * HID;                 // 6.4M
    const long nEH  = (long)N_EDGES * HID;           // 102.4M

    // degrees -> dinv
    hipMemsetAsync(dinv, 0, N_NODES * sizeof(float), stream);
    k_deg<<<(N_EDGES + TB - 1) / TB, TB, 0, stream>>>(dst, dinv);
    k_dinv<<<(N_NODES + TB - 1) / TB, TB, 0, stream>>>(dinv);

    // layer 1
    k_linear<IN_CH><<<(nNH + TB - 1) / TB, TB, 0, stream>>>(x, W1, h);
    hipMemsetAsync(agg, 0, HBYTES, stream);
    k_agg<<<(int)((nEH + TB - 1) / TB), TB, 0, stream>>>(src, dst, dinv, h, agg);
    k_finish<<<(nNH + TB - 1) / TB, TB, 0, stream>>>(h, dinv, b1, agg);

    // layer 2 (input = agg, h overwritten)
    k_linear<HID><<<(nNH + TB - 1) / TB, TB, 0, stream>>>(agg, W2, h);
    hipMemsetAsync(agg, 0, HBYTES, stream);
    k_agg<<<(int)((nEH + TB - 1) / TB), TB, 0, stream>>>(src, dst, dinv, h, agg);
    k_finish<<<(nNH + TB - 1) / TB, TB, 0, stream>>>(h, dinv, b2, agg);

    // pooling
    hipMemsetAsync(pooled, 0, (NG * HID + NG) * sizeof(float), stream);
    k_cnt<<<(N_NODES + TB - 1) / TB, TB, 0, stream>>>(batch, cnt);
    k_pool<<<(nNH + TB - 1) / TB, TB, 0, stream>>>(batch, agg, pooled);

    // head MLP
    k_head<<<NG, 64, 0, stream>>>(pooled, cnt, Wc1, bc1, Wc2, bc2, out);
}

// Round 2
// 822.472 us; speedup vs baseline: 1.6036x; 1.6036x over previous
//
#include <hip/hip_runtime.h>

#define N_NODES 100000
#define N_EDGES 1600000
#define IN_CH   128
#define HID     64
#define NG      256
#define SCAN_CHUNK 1024
#define NB_SCAN ((N_NODES + SCAN_CHUNK - 1) / SCAN_CHUNK)   // 98

// ---- integer degree count over dst ----
__global__ void k_deg(const int* __restrict__ dst, int* __restrict__ deg) {
    int e = blockIdx.x * blockDim.x + threadIdx.x;
    if (e < N_EDGES) atomicAdd(&deg[dst[e]], 1);
}

// ---- dinv[i] = rsqrt(deg[i] + 1) ----
__global__ void k_dinv(const int* __restrict__ deg, float* __restrict__ dinv) {
    int i = blockIdx.x * blockDim.x + threadIdx.x;
    if (i < N_NODES) dinv[i] = rsqrtf((float)deg[i] + 1.0f);
}

// ---- scan step 1: per-1024-chunk exclusive scan + chunk totals ----
__global__ void k_scan1(const int* __restrict__ deg, int* __restrict__ rs,
                        int* __restrict__ bsum) {
    __shared__ int tsum[256];
    int b = blockIdx.x, t = threadIdx.x;
    int base = b * SCAN_CHUNK + t * 4;
    int v[4], s = 0;
#pragma unroll
    for (int k = 0; k < 4; ++k) {
        int idx = base + k;
        v[k] = (idx < N_NODES) ? deg[idx] : 0;
        s += v[k];
    }
    tsum[t] = s;
    __syncthreads();
    for (int off = 1; off < 256; off <<= 1) {
        int add = (t >= off) ? tsum[t - off] : 0;
        __syncthreads();
        tsum[t] += add;
        __syncthreads();
    }
    int excl = tsum[t] - s;
    if (t == 255) bsum[b] = tsum[255];
    int run = excl;
#pragma unroll
    for (int k = 0; k < 4; ++k) {
        int idx = base + k;
        if (idx < N_NODES) rs[idx] = run;
        run += v[k];
    }
}

// ---- scan step 2: serial exclusive scan of chunk totals (98 elems) ----
__global__ void k_scan2(int* __restrict__ bsum) {
    int run = 0;
    for (int b = 0; b < NB_SCAN; ++b) { int v = bsum[b]; bsum[b] = run; run += v; }
}

// ---- scan step 3: add chunk offsets ----
__global__ void k_scan3(int* __restrict__ rs, const int* __restrict__ bsum) {
    int i = blockIdx.x * blockDim.x + threadIdx.x;
    if (i < N_NODES) rs[i] += bsum[i / SCAN_CHUNK];
}

// ---- CSR fill: place each edge in its dst row; precompute norm weight ----
__global__ void k_fill(const int* __restrict__ src, const int* __restrict__ dst,
                       const int* __restrict__ rs, int* __restrict__ fillpos,
                       const float* __restrict__ dinv, int* __restrict__ col,
                       float* __restrict__ wn) {
    int e = blockIdx.x * blockDim.x + threadIdx.x;
    if (e >= N_EDGES) return;
    int s = src[e], d = dst[e];
    int p = atomicAdd(&fillpos[d], 1);
    int idx = rs[d] + p;
    col[idx] = s;
    wn[idx] = dinv[s] * dinv[d];
}

// ---- out[i][j] = sum_k x[i*K+k] * W[k*64+j] ; one wave per node ----
template <int K>
__global__ void k_linear(const float* __restrict__ x, const float* __restrict__ W,
                         float* __restrict__ out) {
    int t = blockIdx.x * blockDim.x + threadIdx.x;
    int i = t >> 6;
    int j = t & 63;
    if (i >= N_NODES) return;
    const float* xr = x + (long)i * K;
    float acc = 0.f;
#pragma unroll 8
    for (int k = 0; k < K; ++k) acc = fmaf(xr[k], W[k * 64 + j], acc);
    out[(long)i * 64 + j] = acc;
}

// ---- fused gather-aggregate + self-loop + bias + relu ----
__global__ void k_gather(const int* __restrict__ rs, const int* __restrict__ deg,
                         const int* __restrict__ col, const float* __restrict__ wn,
                         const float* __restrict__ h, const float* __restrict__ dinv,
                         const float* __restrict__ bias, float* __restrict__ out) {
    int t = blockIdx.x * blockDim.x + threadIdx.x;
    int i = t >> 6;
    int j = t & 63;
    if (i >= N_NODES) return;
    int r0 = rs[i];
    int n = deg[i];
    float acc = 0.f;
    int e = 0;
    for (; e + 4 <= n; e += 4) {
        int   s0 = col[r0 + e + 0], s1 = col[r0 + e + 1];
        int   s2 = col[r0 + e + 2], s3 = col[r0 + e + 3];
        float w0 = wn[r0 + e + 0], w1 = wn[r0 + e + 1];
        float w2 = wn[r0 + e + 2], w3 = wn[r0 + e + 3];
        acc = fmaf(w0, h[s0 * 64 + j], acc);
        acc = fmaf(w1, h[s1 * 64 + j], acc);
        acc = fmaf(w2, h[s2 * 64 + j], acc);
        acc = fmaf(w3, h[s3 * 64 + j], acc);
    }
    for (; e < n; ++e) {
        int s = col[r0 + e];
        acc = fmaf(wn[r0 + e], h[s * 64 + j], acc);
    }
    float di = dinv[i];
    float v = acc + di * di * h[(long)i * 64 + j] + bias[j];
    out[t] = v > 0.f ? v : 0.f;
}

// ---- per-graph node count ----
__global__ void k_cnt(const int* __restrict__ batch, float* __restrict__ cnt) {
    int i = blockIdx.x * blockDim.x + threadIdx.x;
    if (i < N_NODES) atomicAdd(&cnt[batch[i]], 1.0f);
}

// ---- pooled[g][j] += a[i][j] ----
__global__ void k_pool(const int* __restrict__ batch, const float* __restrict__ a,
                       float* __restrict__ pooled) {
    int t = blockIdx.x * blockDim.x + threadIdx.x;
    if (t >= N_NODES * HID) return;
    int i = t >> 6;
    int j = t & 63;
    atomicAdd(&pooled[batch[i] * HID + j], a[t]);
}

// ---- head MLP: one 64-thread block per graph ----
__global__ void k_head(const float* __restrict__ pooled, const float* __restrict__ cnt,
                       const float* __restrict__ Wc1, const float* __restrict__ bc1,
                       const float* __restrict__ Wc2, const float* __restrict__ bc2,
                       float* __restrict__ out) {
    __shared__ float gvec[64];
    __shared__ float tvec[32];
    int g = blockIdx.x;
    int j = threadIdx.x;
    float c = cnt[g];
    c = c > 1.f ? c : 1.f;
    gvec[j] = pooled[g * 64 + j] / c;
    __syncthreads();
    if (j < 32) {
        float acc = bc1[j];
#pragma unroll 8
        for (int k = 0; k < 64; ++k) acc = fmaf(gvec[k], Wc1[k * 32 + j], acc);
        tvec[j] = acc > 0.f ? acc : 0.f;
    }
    __syncthreads();
    if (j < 2) {
        float acc = bc2[j];
#pragma unroll
        for (int k = 0; k < 32; ++k) acc = fmaf(tvec[k], Wc2[k * 2 + j], acc);
        out[g * 2 + j] = acc;
    }
}

extern "C" void kernel_launch(void* const* d_in, const int* in_sizes, int n_in,
                              void* d_out, int out_size, void* d_ws, size_t ws_size,
                              hipStream_t stream) {
    const float* x    = (const float*)d_in[0];
    const int*   ei   = (const int*)d_in[1];
    const int*   batch= (const int*)d_in[2];
    const float* W1   = (const float*)d_in[3];
    const float* b1   = (const float*)d_in[4];
    const float* W2   = (const float*)d_in[5];
    const float* b2   = (const float*)d_in[6];
    const float* Wc1  = (const float*)d_in[7];
    const float* bc1  = (const float*)d_in[8];
    const float* Wc2  = (const float*)d_in[9];
    const float* bc2  = (const float*)d_in[10];
    float* out = (float*)d_out;

    const int* src = ei;            // edge_index[0]
    const int* dst = ei + N_EDGES;  // edge_index[1]

    // workspace layout (running offsets, 256B aligned)
    char* ws = (char*)d_ws;
    size_t off = 0;
    auto alloc = [&](size_t bytes) {
        void* p = ws + off;
        off += (bytes + 255) & ~(size_t)255;
        return p;
    };
    float* h       = (float*)alloc((size_t)N_NODES * HID * sizeof(float)); // 25.6MB
    float* agg     = (float*)alloc((size_t)N_NODES * HID * sizeof(float)); // 25.6MB
    float* dinv    = (float*)alloc(N_NODES * sizeof(float));
    int*   deg     = (int*)  alloc(N_NODES * sizeof(int));
    int*   rs      = (int*)  alloc((N_NODES + 1) * sizeof(int));
    int*   fillpos = (int*)  alloc(N_NODES * sizeof(int));
    int*   col     = (int*)  alloc((size_t)N_EDGES * sizeof(int));   // 6.4MB
    float* wn      = (float*)alloc((size_t)N_EDGES * sizeof(float)); // 6.4MB
    int*   bsum    = (int*)  alloc(NB_SCAN * sizeof(int));
    float* pooled  = (float*)alloc(NG * HID * sizeof(float));
    float* cnt     = (float*)alloc(NG * sizeof(float));

    const int TB = 256;
    const int nNH = N_NODES * HID;  // 6.4M

    // CSR build
    hipMemsetAsync(deg, 0, N_NODES * sizeof(int), stream);
    hipMemsetAsync(fillpos, 0, N_NODES * sizeof(int), stream);
    k_deg<<<(N_EDGES + TB - 1) / TB, TB, 0, stream>>>(dst, deg);
    k_dinv<<<(N_NODES + TB - 1) / TB, TB, 0, stream>>>(deg, dinv);
    k_scan1<<<NB_SCAN, 256, 0, stream>>>(deg, rs, bsum);
    k_scan2<<<1, 1, 0, stream>>>(bsum);
    k_scan3<<<(N_NODES + TB - 1) / TB, TB, 0, stream>>>(rs, bsum);
    k_fill<<<(N_EDGES + TB - 1) / TB, TB, 0, stream>>>(src, dst, rs, fillpos, dinv, col, wn);

    // layer 1
    k_linear<IN_CH><<<(nNH + TB - 1) / TB, TB, 0, stream>>>(x, W1, h);
    k_gather<<<(nNH + TB - 1) / TB, TB, 0, stream>>>(rs, deg, col, wn, h, dinv, b1, agg);

    // layer 2
    k_linear<HID><<<(nNH + TB - 1) / TB, TB, 0, stream>>>(agg, W2, h);
    k_gather<<<(nNH + TB - 1) / TB, TB, 0, stream>>>(rs, deg, col, wn, h, dinv, b2, agg);

    // pooling
    hipMemsetAsync(pooled, 0, (NG * HID + NG) * sizeof(float), stream);
    hipMemsetAsync(cnt, 0, NG * sizeof(float), stream);
    k_cnt<<<(N_NODES + TB - 1) / TB, TB, 0, stream>>>(batch, cnt);
    k_pool<<<(nNH + TB - 1) / TB, TB, 0, stream>>>(batch, agg, pooled);

    // head MLP
    k_head<<<NG, 64, 0, stream>>>(pooled, cnt, Wc1, bc1, Wc2, bc2, out);
}

// Round 3
// 413.797 us; speedup vs baseline: 3.1874x; 1.9876x over previous
//
#include <hip/hip_runtime.h>

#define N_NODES 100000
#define N_EDGES 1600000
#define IN_CH   128
#define HID     64
#define NG      256
#define SCAN_CHUNK 1024
#define NB_SCAN ((N_NODES + SCAN_CHUNK - 1) / SCAN_CHUNK)   // 98

// ---- integer degree count over dst ----
__global__ void k_deg(const int* __restrict__ dst, int* __restrict__ deg) {
    int e = blockIdx.x * blockDim.x + threadIdx.x;
    if (e < N_EDGES) atomicAdd(&deg[dst[e]], 1);
}

// ---- dinv[i] = rsqrt(deg[i] + 1) ----
__global__ void k_dinv(const int* __restrict__ deg, float* __restrict__ dinv) {
    int i = blockIdx.x * blockDim.x + threadIdx.x;
    if (i < N_NODES) dinv[i] = rsqrtf((float)deg[i] + 1.0f);
}

// ---- scan step 1: per-1024-chunk exclusive scan + chunk totals ----
__global__ void k_scan1(const int* __restrict__ deg, int* __restrict__ rs,
                        int* __restrict__ bsum) {
    __shared__ int tsum[256];
    int b = blockIdx.x, t = threadIdx.x;
    int base = b * SCAN_CHUNK + t * 4;
    int v[4], s = 0;
#pragma unroll
    for (int k = 0; k < 4; ++k) {
        int idx = base + k;
        v[k] = (idx < N_NODES) ? deg[idx] : 0;
        s += v[k];
    }
    tsum[t] = s;
    __syncthreads();
    for (int off = 1; off < 256; off <<= 1) {
        int add = (t >= off) ? tsum[t - off] : 0;
        __syncthreads();
        tsum[t] += add;
        __syncthreads();
    }
    int excl = tsum[t] - s;
    if (t == 255) bsum[b] = tsum[255];
    int run = excl;
#pragma unroll
    for (int k = 0; k < 4; ++k) {
        int idx = base + k;
        if (idx < N_NODES) rs[idx] = run;
        run += v[k];
    }
}

// ---- scan step 2: serial exclusive scan of chunk totals ----
__global__ void k_scan2(int* __restrict__ bsum) {
    int run = 0;
    for (int b = 0; b < NB_SCAN; ++b) { int v = bsum[b]; bsum[b] = run; run += v; }
}

// ---- scan step 3: add chunk offsets ----
__global__ void k_scan3(int* __restrict__ rs, const int* __restrict__ bsum) {
    int i = blockIdx.x * blockDim.x + threadIdx.x;
    if (i < N_NODES) rs[i] += bsum[i / SCAN_CHUNK];
}

// ---- CSR fill: place each edge in its dst row; precompute norm weight ----
__global__ void k_fill(const int* __restrict__ src, const int* __restrict__ dst,
                       const int* __restrict__ rs, int* __restrict__ fillpos,
                       const float* __restrict__ dinv, int* __restrict__ col,
                       float* __restrict__ wn) {
    int e = blockIdx.x * blockDim.x + threadIdx.x;
    if (e >= N_EDGES) return;
    int s = src[e], d = dst[e];
    int p = atomicAdd(&fillpos[d], 1);
    int idx = rs[d] + p;
    col[idx] = s;
    wn[idx] = dinv[s] * dinv[d];
}

// ---- LDS-tiled linear: 16 nodes/block, wave computes 4 nodes x 64 ch ----
// out[i][j] = sum_k x[i][k] * W[k][j]
template <int K>
__global__ void __launch_bounds__(256) k_linear(const float* __restrict__ x,
                                                const float* __restrict__ W,
                                                float* __restrict__ out) {
    __shared__ float ws[K * 64];    // W tile (whole W)
    __shared__ float xs[16 * K];    // 16 node rows
    const int tid = threadIdx.x;

    // stage W (coalesced float4, linear LDS)
    const float4* W4 = reinterpret_cast<const float4*>(W);
    float4* ws4 = reinterpret_cast<float4*>(ws);
    for (int idx = tid; idx < K * 16; idx += 256) ws4[idx] = W4[idx];

    // stage x rows (coalesced float4, linear LDS)
    const float4* x4 = reinterpret_cast<const float4*>(x + (long)blockIdx.x * 16 * K);
    float4* xs4 = reinterpret_cast<float4*>(xs);
    for (int idx = tid; idx < 16 * (K / 4); idx += 256) xs4[idx] = x4[idx];
    __syncthreads();

    const int w = tid >> 6;    // wave -> nodes w*4 .. w*4+3
    const int j = tid & 63;    // output channel
    float a0 = 0.f, a1 = 0.f, a2 = 0.f, a3 = 0.f;
    const float4* xr0 = reinterpret_cast<const float4*>(xs + (w * 4 + 0) * K);
    const float4* xr1 = reinterpret_cast<const float4*>(xs + (w * 4 + 1) * K);
    const float4* xr2 = reinterpret_cast<const float4*>(xs + (w * 4 + 2) * K);
    const float4* xr3 = reinterpret_cast<const float4*>(xs + (w * 4 + 3) * K);
#pragma unroll 4
    for (int k4 = 0; k4 < K / 4; ++k4) {
        float4 xq0 = xr0[k4];
        float4 xq1 = xr1[k4];
        float4 xq2 = xr2[k4];
        float4 xq3 = xr3[k4];
        float w0 = ws[(4 * k4 + 0) * 64 + j];
        float w1 = ws[(4 * k4 + 1) * 64 + j];
        float w2 = ws[(4 * k4 + 2) * 64 + j];
        float w3 = ws[(4 * k4 + 3) * 64 + j];
        a0 = fmaf(xq0.x, w0, a0); a0 = fmaf(xq0.y, w1, a0);
        a0 = fmaf(xq0.z, w2, a0); a0 = fmaf(xq0.w, w3, a0);
        a1 = fmaf(xq1.x, w0, a1); a1 = fmaf(xq1.y, w1, a1);
        a1 = fmaf(xq1.z, w2, a1); a1 = fmaf(xq1.w, w3, a1);
        a2 = fmaf(xq2.x, w0, a2); a2 = fmaf(xq2.y, w1, a2);
        a2 = fmaf(xq2.z, w2, a2); a2 = fmaf(xq2.w, w3, a2);
        a3 = fmaf(xq3.x, w0, a3); a3 = fmaf(xq3.y, w1, a3);
        a3 = fmaf(xq3.z, w2, a3); a3 = fmaf(xq3.w, w3, a3);
    }
    long base = ((long)blockIdx.x * 16 + w * 4) * 64 + j;
    out[base]       = a0;
    out[base + 64]  = a1;
    out[base + 128] = a2;
    out[base + 192] = a3;
}

// ---- fused gather-aggregate + self-loop + bias + relu ----
__global__ void k_gather(const int* __restrict__ rs, const int* __restrict__ deg,
                         const int* __restrict__ col, const float* __restrict__ wn,
                         const float* __restrict__ h, const float* __restrict__ dinv,
                         const float* __restrict__ bias, float* __restrict__ out) {
    int t = blockIdx.x * blockDim.x + threadIdx.x;
    int i = t >> 6;
    int j = t & 63;
    if (i >= N_NODES) return;
    int r0 = rs[i];
    int n = deg[i];
    float acc = 0.f;
    int e = 0;
    for (; e + 4 <= n; e += 4) {
        int   s0 = col[r0 + e + 0], s1 = col[r0 + e + 1];
        int   s2 = col[r0 + e + 2], s3 = col[r0 + e + 3];
        float w0 = wn[r0 + e + 0], w1 = wn[r0 + e + 1];
        float w2 = wn[r0 + e + 2], w3 = wn[r0 + e + 3];
        acc = fmaf(w0, h[s0 * 64 + j], acc);
        acc = fmaf(w1, h[s1 * 64 + j], acc);
        acc = fmaf(w2, h[s2 * 64 + j], acc);
        acc = fmaf(w3, h[s3 * 64 + j], acc);
    }
    for (; e < n; ++e) {
        int s = col[r0 + e];
        acc = fmaf(wn[r0 + e], h[s * 64 + j], acc);
    }
    float di = dinv[i];
    float v = acc + di * di * h[(long)i * 64 + j] + bias[j];
    out[t] = v > 0.f ? v : 0.f;
}

// ---- graph boundaries from sorted batch: start[g] for g in [0,NG] ----
__global__ void k_bounds(const int* __restrict__ batch, int* __restrict__ start) {
    int i = blockIdx.x * blockDim.x + threadIdx.x;
    if (i >= N_NODES) return;
    int b = batch[i];
    int prev = (i == 0) ? -1 : batch[i - 1];
    for (int g = prev + 1; g <= b; ++g) start[g] = i;
    if (i == N_NODES - 1)
        for (int g = b + 1; g <= NG; ++g) start[g] = N_NODES;
}

// ---- fused mean-pool + head MLP: one 256-thread block per graph ----
__global__ void k_poolhead(const float* __restrict__ a, const int* __restrict__ start,
                           const float* __restrict__ Wc1, const float* __restrict__ bc1,
                           const float* __restrict__ Wc2, const float* __restrict__ bc2,
                           float* __restrict__ out) {
    __shared__ float partial[4][64];
    __shared__ float gvec[64];
    __shared__ float tvec[32];
    int g = blockIdx.x;
    int w = threadIdx.x >> 6;
    int j = threadIdx.x & 63;
    int s0 = start[g], s1 = start[g + 1];
    float acc = 0.f;
    for (int i = s0 + w; i < s1; i += 4)
        acc += a[(long)i * 64 + j];
    partial[w][j] = acc;
    __syncthreads();
    if (w == 0) {
        float c = (float)(s1 - s0);
        c = c > 1.f ? c : 1.f;
        gvec[j] = (partial[0][j] + partial[1][j] + partial[2][j] + partial[3][j]) / c;
    }
    __syncthreads();
    if (threadIdx.x < 32) {
        int jj = threadIdx.x;
        float acc2 = bc1[jj];
#pragma unroll 8
        for (int k = 0; k < 64; ++k) acc2 = fmaf(gvec[k], Wc1[k * 32 + jj], acc2);
        tvec[jj] = acc2 > 0.f ? acc2 : 0.f;
    }
    __syncthreads();
    if (threadIdx.x < 2) {
        int jj = threadIdx.x;
        float acc2 = bc2[jj];
#pragma unroll
        for (int k = 0; k < 32; ++k) acc2 = fmaf(tvec[k], Wc2[k * 2 + jj], acc2);
        out[g * 2 + jj] = acc2;
    }
}

extern "C" void kernel_launch(void* const* d_in, const int* in_sizes, int n_in,
                              void* d_out, int out_size, void* d_ws, size_t ws_size,
                              hipStream_t stream) {
    const float* x    = (const float*)d_in[0];
    const int*   ei   = (const int*)d_in[1];
    const int*   batch= (const int*)d_in[2];
    const float* W1   = (const float*)d_in[3];
    const float* b1   = (const float*)d_in[4];
    const float* W2   = (const float*)d_in[5];
    const float* b2   = (const float*)d_in[6];
    const float* Wc1  = (const float*)d_in[7];
    const float* bc1  = (const float*)d_in[8];
    const float* Wc2  = (const float*)d_in[9];
    const float* bc2  = (const float*)d_in[10];
    float* out = (float*)d_out;

    const int* src = ei;            // edge_index[0]
    const int* dst = ei + N_EDGES;  // edge_index[1]

    // workspace layout (running offsets, 256B aligned)
    char* ws = (char*)d_ws;
    size_t off = 0;
    auto alloc = [&](size_t bytes) {
        void* p = ws + off;
        off += (bytes + 255) & ~(size_t)255;
        return p;
    };
    float* h       = (float*)alloc((size_t)N_NODES * HID * sizeof(float)); // 25.6MB
    float* agg     = (float*)alloc((size_t)N_NODES * HID * sizeof(float)); // 25.6MB
    float* dinv    = (float*)alloc(N_NODES * sizeof(float));
    int*   deg     = (int*)  alloc(N_NODES * sizeof(int));
    int*   rs      = (int*)  alloc((N_NODES + 1) * sizeof(int));
    int*   fillpos = (int*)  alloc(N_NODES * sizeof(int));
    int*   col     = (int*)  alloc((size_t)N_EDGES * sizeof(int));   // 6.4MB
    float* wn      = (float*)alloc((size_t)N_EDGES * sizeof(float)); // 6.4MB
    int*   bsum    = (int*)  alloc(NB_SCAN * sizeof(int));
    int*   start   = (int*)  alloc((NG + 1) * sizeof(int));

    const int TB = 256;
    const int nNH = N_NODES * HID;  // 6.4M

    // CSR build
    hipMemsetAsync(deg, 0, N_NODES * sizeof(int), stream);
    hipMemsetAsync(fillpos, 0, N_NODES * sizeof(int), stream);
    k_deg<<<(N_EDGES + TB - 1) / TB, TB, 0, stream>>>(dst, deg);
    k_dinv<<<(N_NODES + TB - 1) / TB, TB, 0, stream>>>(deg, dinv);
    k_scan1<<<NB_SCAN, 256, 0, stream>>>(deg, rs, bsum);
    k_scan2<<<1, 1, 0, stream>>>(bsum);
    k_scan3<<<(N_NODES + TB - 1) / TB, TB, 0, stream>>>(rs, bsum);
    k_fill<<<(N_EDGES + TB - 1) / TB, TB, 0, stream>>>(src, dst, rs, fillpos, dinv, col, wn);

    // graph boundaries (for pooling)
    k_bounds<<<(N_NODES + TB - 1) / TB, TB, 0, stream>>>(batch, start);

    // layer 1
    k_linear<IN_CH><<<N_NODES / 16, 256, 0, stream>>>(x, W1, h);
    k_gather<<<(nNH + TB - 1) / TB, TB, 0, stream>>>(rs, deg, col, wn, h, dinv, b1, agg);

    // layer 2
    k_linear<HID><<<N_NODES / 16, 256, 0, stream>>>(agg, W2, h);
    k_gather<<<(nNH + TB - 1) / TB, TB, 0, stream>>>(rs, deg, col, wn, h, dinv, b2, agg);

    // fused mean-pool + head
    k_poolhead<<<NG, 256, 0, stream>>>(agg, start, Wc1, bc1, Wc2, bc2, out);
}